// Round 1
// baseline (69.898 us; speedup 1.0000x reference)
//
#include <hip/hip_runtime.h>
#include <hip/hip_bf16.h>

#define T_LEN 2400
#define LPC_N 16
#define FRAME 160
#define CHUNK 240
#define BLOCK 256

// sig: (B, T, 1) float32 in [0,255); lpc: (B, 15, 16) float32; out: (B, T, 1) float32
__global__ __launch_bounds__(BLOCK)
void diff_pred_26319559589961_kernel(const float* __restrict__ sig,
                                     const float* __restrict__ lpc,
                                     float* __restrict__ out)
{
    __shared__ float xs[BLOCK];   // decoded linear samples covering [t0-16, t0+CHUNK)

    const int b   = blockIdx.y;
    const int t0  = blockIdx.x * CHUNK;
    const int tid = threadIdx.x;

    // ---- phase 1: mu-law decode (u2l), one sample per thread, halo of LPC_N ----
    // u2l(v) = sign(v-128) * (32768/255) * (exp((|v-128|/128)*ln256) - 1)
    //        = sign(u) * (32768/255) * (2^(|u|/16) - 1)
    {
        const int t_in = t0 - LPC_N + tid;
        float x = 0.0f;
        if (t_in >= 0) {
            const float u  = sig[b * T_LEN + t_in] - 128.0f;
            const float au = fabsf(u);
            x = copysignf((32768.0f / 255.0f) * (exp2f(au * 0.0625f) - 1.0f), u);
        }
        xs[tid] = x;
    }
    __syncthreads();

    // ---- phase 2: 16-tap LPC prediction + l2u re-encode ----
    if (tid < CHUNK) {
        const int t     = t0 + tid;
        const int frame = t / FRAME;                       // per-frame coeffs
        const float4* c = (const float4*)(lpc + ((size_t)b * 15 + frame) * LPC_N);
        const float4 c0 = c[0];
        const float4 c1 = c[1];
        const float4 c2 = c[2];
        const float4 c3 = c[3];

        const int base = LPC_N + tid;                      // xs[base - i] == xt[b, t - i]
        float acc = 0.0f;
        acc += c0.x * xs[base -  0];
        acc += c0.y * xs[base -  1];
        acc += c0.z * xs[base -  2];
        acc += c0.w * xs[base -  3];
        acc += c1.x * xs[base -  4];
        acc += c1.y * xs[base -  5];
        acc += c1.z * xs[base -  6];
        acc += c1.w * xs[base -  7];
        acc += c2.x * xs[base -  8];
        acc += c2.y * xs[base -  9];
        acc += c2.z * xs[base - 10];
        acc += c2.w * xs[base - 11];
        acc += c3.x * xs[base - 12];
        acc += c3.y * xs[base - 13];
        acc += c3.z * xs[base - 14];
        acc += c3.w * xs[base - 15];

        const float pred = -acc;
        // l2u(p) = clip(128 + sign(p) * 128 * log1p((255/32768)*|p|)/ln256, 0, 255)
        //        = clip(128 + sign(p) * 16 * log2(1 + (255/32768)*|p|), 0, 255)
        const float ap = fabsf(pred);
        const float u  = copysignf(16.0f * __log2f(1.0f + (255.0f / 32768.0f) * ap), pred);
        out[(size_t)b * T_LEN + t] = fminf(fmaxf(128.0f + u, 0.0f), 255.0f);
    }
}

extern "C" void kernel_launch(void* const* d_in, const int* in_sizes, int n_in,
                              void* d_out, int out_size, void* d_ws, size_t ws_size,
                              hipStream_t stream) {
    const float* sig = (const float*)d_in[0];   // (B, 2400, 1)
    const float* lpc = (const float*)d_in[1];   // (B, 15, 16)
    float* out = (float*)d_out;                 // (B, 2400, 1)

    const int B = in_sizes[0] / T_LEN;
    dim3 grid(T_LEN / CHUNK, B);
    diff_pred_26319559589961_kernel<<<grid, BLOCK, 0, stream>>>(sig, lpc, out);
}

// Round 2
// 65.102 us; speedup vs baseline: 1.0737x; 1.0737x over previous
//
#include <hip/hip_runtime.h>
#include <hip/hip_bf16.h>

#define T_LEN 2400
#define LPC_N 16
#define FRAME 160
#define CHUNK 800          // samples per block (divides T_LEN, multiple of FRAME? 800 = 5 frames)
#define NGRP  (CHUNK / 4)  // 200 groups of 4 outputs
#define BLOCK 256

// sig: (B, 2400, 1) f32 in [0,255); lpc: (B, 15, 16) f32; out: (B, 2400, 1) f32
__global__ __launch_bounds__(BLOCK)
void diff_pred_26319559589961_kernel(const float* __restrict__ sig,
                                     const float* __restrict__ lpc,
                                     float* __restrict__ out)
{
    // decoded linear samples covering [t0-16, t0+CHUNK)  -> 816 floats
    __shared__ float xs[CHUNK + LPC_N];

    const int b   = blockIdx.y;
    const int t0  = blockIdx.x * CHUNK;
    const int tid = threadIdx.x;

    // ---- phase 1: mu-law decode, float4 per thread (204 groups of 4 samples) ----
    // u2l(v) = copysign((32768/255) * (2^(|v-128|/16) - 1), v-128)
    if (tid < (CHUNK + LPC_N) / 4) {
        const int t_in = t0 - LPC_N + 4 * tid;       // aligned: t0-16 ≡ 0 (mod 4)
        float4 r;
        if (t_in >= 0) {
            const float4 v = *(const float4*)(sig + (size_t)b * T_LEN + t_in);
            const float ux = v.x - 128.0f, uy = v.y - 128.0f,
                        uz = v.z - 128.0f, uw = v.w - 128.0f;
            r.x = copysignf((32768.0f/255.0f) * (exp2f(fabsf(ux) * 0.0625f) - 1.0f), ux);
            r.y = copysignf((32768.0f/255.0f) * (exp2f(fabsf(uy) * 0.0625f) - 1.0f), uy);
            r.z = copysignf((32768.0f/255.0f) * (exp2f(fabsf(uz) * 0.0625f) - 1.0f), uz);
            r.w = copysignf((32768.0f/255.0f) * (exp2f(fabsf(uw) * 0.0625f) - 1.0f), uw);
        } else {
            r = make_float4(0.0f, 0.0f, 0.0f, 0.0f); // history pad for first chunk
        }
        *(float4*)(xs + 4 * tid) = r;                // ds_write_b128, aligned
    }
    __syncthreads();

    // ---- phase 2: 4 outputs per thread ----
    if (tid < NGRP) {
        const int t     = t0 + 4 * tid;              // group start; 160 % 4 == 0 so
        const int frame = t / FRAME;                 // one frame per group
        const float4* c = (const float4*)(lpc + ((size_t)b * 15 + frame) * LPC_N);
        const float4 c0 = c[0], c1 = c[1], c2 = c[2], c3 = c[3];

        // r[m] = xs[4*tid + m], m = 0..19  (5 aligned ds_read_b128)
        float r[20];
        *(float4*)(r +  0) = *(const float4*)(xs + 4 * tid +  0);
        *(float4*)(r +  4) = *(const float4*)(xs + 4 * tid +  4);
        *(float4*)(r +  8) = *(const float4*)(xs + 4 * tid +  8);
        *(float4*)(r + 12) = *(const float4*)(xs + 4 * tid + 12);
        *(float4*)(r + 16) = *(const float4*)(xs + 4 * tid + 16);

        const float cf[16] = { c0.x, c0.y, c0.z, c0.w,
                               c1.x, c1.y, c1.z, c1.w,
                               c2.x, c2.y, c2.z, c2.w,
                               c3.x, c3.y, c3.z, c3.w };

        float4 o;
        float* op = &o.x;
        #pragma unroll
        for (int k = 0; k < 4; ++k) {
            float acc = 0.0f;
            #pragma unroll
            for (int i = 0; i < LPC_N; ++i)
                acc += cf[i] * r[16 + k - i];
            const float pred = -acc;
            // l2u(p) = clip(128 + copysign(16*log2(1 + (255/32768)|p|), p), 0, 255)
            const float u = copysignf(
                16.0f * __log2f(1.0f + (255.0f/32768.0f) * fabsf(pred)), pred);
            op[k] = fminf(fmaxf(128.0f + u, 0.0f), 255.0f);
        }
        *(float4*)(out + (size_t)b * T_LEN + t) = o;  // global_store_dwordx4
    }
}

extern "C" void kernel_launch(void* const* d_in, const int* in_sizes, int n_in,
                              void* d_out, int out_size, void* d_ws, size_t ws_size,
                              hipStream_t stream) {
    const float* sig = (const float*)d_in[0];   // (B, 2400, 1)
    const float* lpc = (const float*)d_in[1];   // (B, 15, 16)
    float* out = (float*)d_out;                 // (B, 2400, 1)

    const int B = in_sizes[0] / T_LEN;
    dim3 grid(T_LEN / CHUNK, B);                // (3, 1024)
    diff_pred_26319559589961_kernel<<<grid, BLOCK, 0, stream>>>(sig, lpc, out);
}